// Round 18
// baseline (726.912 us; speedup 1.0000x reference)
//
#include <hip/hip_runtime.h>

#define BTOT    524288
#define NMT     32768          // 16-row microtiles
#define NWAVE   4096           // 256 blocks x 16 waves
#define TN      6              // Taylor order for expm (theta<=1 -> rem ~2.2e-4)

typedef __attribute__((ext_vector_type(8))) short s8v;     // 8 x bf16 bits
typedef __attribute__((ext_vector_type(4))) short s4v;     // 4 x bf16 bits (b64)
typedef __attribute__((ext_vector_type(4))) float f4v;
typedef __attribute__((ext_vector_type(4))) unsigned u32x4;

#define MFMA(a,b,c) __builtin_amdgcn_mfma_f32_16x16x32_bf16((a),(b),(c),0,0,0)
#define BCV(x) __builtin_bit_cast(s8v, x)

__device__ __forceinline__ short f2b(float f) {            // f32 -> bf16 (RNE)
  union { float f; unsigned u; } v; v.f = f;
  unsigned r = v.u + 0x7fffu + ((v.u >> 16) & 1u);
  return (short)(r >> 16);
}
__device__ __forceinline__ float b2f(short s) {
  union { float f; unsigned u; } v; v.u = ((unsigned)(unsigned short)s) << 16;
  return v.f;
}
__device__ __forceinline__ unsigned bfb(float f) {         // bf16 bits in low16
  union { float f; unsigned u; } v; v.f = f;
  return (v.u + 0x7fffu + ((v.u >> 16) & 1u)) >> 16;
}
// packed pair, round-half-up (<=0.5 ulp): 2 adds + 1 v_perm_b32 (r12-proven)
__device__ __forceinline__ unsigned pk2(float a, float b) {
#if __has_builtin(__builtin_amdgcn_perm)
  unsigned ua = __builtin_bit_cast(unsigned, a) + 0x8000u;
  unsigned ub = __builtin_bit_cast(unsigned, b) + 0x8000u;
  return __builtin_amdgcn_perm(ub, ua, 0x07060302u);   // {hi16(ub), hi16(ua)}
#else
  return bfb(a) | (bfb(b) << 16);
#endif
}
__device__ __forceinline__ unsigned pk2r(float a, float b) { return pk2(fmaxf(a,0.f), fmaxf(b,0.f)); }
__device__ __forceinline__ s8v pack8(f4v u, f4v v) {
  u32x4 w = {pk2(u[0],u[1]), pk2(u[2],u[3]), pk2(v[0],v[1]), pk2(v[2],v[3])};
  return BCV(w);
}

// prep-only: MFMA fragment load from padded row-major LDS tile
__device__ __forceinline__ s8v ldfrag(const short* base, int row0, int kbase, int stride) {
  const int l = threadIdx.x & 63;
  return *(const s8v*)(base + (row0 + (l & 15)) * stride + kbase + (l >> 4) * 8);
}
// frag-linear chunk read: lane-linear 16B -> conflict-free
__device__ __forceinline__ s8v ldw(const short* base, int chunk) {
  return *(const s8v*)(base + (chunk * 64 + (threadIdx.x & 63)) * 8);
}

// ---- ws layout (shorts): fragment-linear packed weights ----
#define WS_M1   0        // [128][64]  KS=2  (k natural: X)
#define WS_I1   8192     // [96][128]  KS=4  (k phinv:   Z)
#define WS_W1   20480    // [96][64]   KS=2  (k natural: X)
#define WS_W2K  26624    // [128][96]  KS=3  (k phinv:   H)
#define WS_I2   38912    // [64][96]   KS=3  (k phinv:   H2)

__device__ __forceinline__ int fragidx(int n, int k, int KS) {
  int jj = n >> 4, ks = k >> 5;
  int l = (n & 15) | (((k >> 3) & 3) << 4);
  return ((jj * KS + ks) * 64 + l) * 8 + (k & 7);
}
// feature-index permutation absorbing D-frag->B-frag layout: swap bit4 <-> bits3:2
__device__ __forceinline__ int phinv(int f) {
  return (f & ~31) | (((f >> 2) & 3) << 3) | (((f >> 4) & 1) << 2) | (f & 3);
}

// ---------------------------------------------------------------------------
// Kernel 1: expm(A*t/24) via scaling+squaring Taylor (split-bf16 MFMA), then
// emit ALL weights as bf16 fragment-linear buffers in ws. (r16 version —
// scatter->LDS staging->coalesced copy; validated)
// ---------------------------------------------------------------------------
__global__ __launch_bounds__(512, 2) void koop_prep(
    const float* __restrict__ tptr, const float* __restrict__ Ag,
    const float* __restrict__ W2g, const float* __restrict__ w1g,
    const float* __restrict__ i1g, const float* __restrict__ i2g,
    short* __restrict__ wsp) {
  extern __shared__ __align__(16) char smem[];
  short* RThi = (short*)smem;              // [128][136]
  short* RTlo = RThi + 128 * 136;          // [128][136]
  float* sW2  = (float*)(RTlo + 128 * 136);// [128][96]
  float* sred = sW2 + 128 * 96;            // [130]
  float* scratch = (float*)smem;           // [128][128] f32 alias
  short* pkst = RThi;                      // pack staging (pre-expm, 24KB max)

  const int tid = threadIdx.x;
  const int lane = tid & 63, wid = tid >> 6;
  const int c_ = lane & 15, g_ = lane >> 4;
  const int mr = wid * 16;

  // W2 raw staging (disjoint region, can run early)
  for (int i = tid; i < 128 * 96; i += 512) sW2[i] = W2g[i];

  // ---- raw-weight packing: scatter->LDS, coalesced copy->global ----
  for (int e = tid; e < 6144; e += 512)
    pkst[fragidx(e >> 6, e & 63, 2)] = f2b(w1g[e]);
  __syncthreads();
  for (int i = tid; i < 768; i += 512)
    ((f4v*)(wsp + WS_W1))[i] = ((const f4v*)pkst)[i];
  __syncthreads();
  for (int e = tid; e < 12288; e += 512)
    pkst[fragidx(e >> 7, phinv(e & 127), 4)] = f2b(i1g[e]);
  __syncthreads();
  for (int i = tid; i < 1536; i += 512)
    ((f4v*)(wsp + WS_I1))[i] = ((const f4v*)pkst)[i];
  __syncthreads();
  for (int e = tid; e < 6144; e += 512)
    pkst[fragidx(e / 96, phinv(e % 96), 3)] = f2b(i2g[e]);
  __syncthreads();
  for (int i = tid; i < 768; i += 512)
    ((f4v*)(wsp + WS_I2))[i] = ((const f4v*)pkst)[i];
  __syncthreads();

  const float s = tptr[0] * (1.0f / 24.0f);
  for (int i = tid; i < 128 * 128; i += 512) scratch[i] = Ag[i] * s;
  __syncthreads();

  {  // inf-norm: 4 threads/row, shuffle-reduce
    const int row = tid >> 2, q = tid & 3;
    float su = 0.f;
    const float* rp = scratch + row * 128 + q * 32;
#pragma unroll 8
    for (int j = 0; j < 32; ++j) su += fabsf(rp[j]);
    su += __shfl_xor(su, 1);
    su += __shfl_xor(su, 2);
    if (q == 0) sred[row] = su;
  }
  __syncthreads();
  if (tid < 64) {
    float m = fmaxf(sred[tid], sred[tid + 64]);
#pragma unroll
    for (int d = 32; d; d >>= 1) m = fmaxf(m, __shfl_xor(m, d));
    if (tid == 0) {
      int j = 0;
      if (m > 1.0f) {
        j = (int)ceilf(log2f(m));
        if (j < 0) j = 0; if (j > 20) j = 20;
      }
      sred[128] = (float)j; sred[129] = exp2f(-(float)j);
    }
  }
  __syncthreads();
  const int jsq = (int)sred[128];
  const float sc = sred[129];

  s8v Ahi[4], Alo[4];
#pragma unroll
  for (int ks = 0; ks < 4; ++ks) {
    const float* p = scratch + (mr + c_) * 128 + ks * 32 + g_ * 8;
    f4v u = *(const f4v*)p, v = *(const f4v*)(p + 4);
    float vals[8] = {u[0], u[1], u[2], u[3], v[0], v[1], v[2], v[3]};
#pragma unroll
    for (int i = 0; i < 8; ++i) {
      float y = vals[i] * sc;
      short h = f2b(y);
      Ahi[ks][i] = h;
      Alo[ks][i] = f2b(y - b2f(h));
    }
  }
  float yv[32];
#pragma unroll
  for (int e = 0; e < 32; ++e) yv[e] = scratch[tid * 32 + e];
  __syncthreads();

#pragma unroll
  for (int e = 0; e < 32; ++e) {
    int idx = tid * 32 + e;
    int r = idx >> 7, c = idx & 127;
    float v = yv[e] * sc * (1.0f / TN) + ((r == c) ? 1.0f : 0.0f);
    short h = f2b(v);
    RThi[c * 136 + r] = h;
    RTlo[c * 136 + r] = f2b(v - b2f(h));
  }
  __syncthreads();

  for (int k = TN - 1; k >= 1; --k) {
    f4v acc[8];
#pragma unroll
    for (int nt = 0; nt < 8; ++nt) acc[nt] = (f4v){0.f, 0.f, 0.f, 0.f};
#pragma unroll
    for (int ks = 0; ks < 4; ++ks) {
#pragma unroll
      for (int nt = 0; nt < 8; ++nt) {
        s8v bh = ldfrag(RThi, nt * 16, ks * 32, 136);
        s8v bl = ldfrag(RTlo, nt * 16, ks * 32, 136);
        acc[nt] = MFMA(Ahi[ks], bh, acc[nt]);
        acc[nt] = MFMA(Alo[ks], bh, acc[nt]);
        acc[nt] = MFMA(Ahi[ks], bl, acc[nt]);
      }
    }
    __syncthreads();
    const float invk = 1.0f / (float)k;
    const int row0 = mr + g_ * 4;
#pragma unroll
    for (int nt = 0; nt < 8; ++nt) {
      const int col = nt * 16 + c_;
      s4v hi, lo;
#pragma unroll
      for (int r = 0; r < 4; ++r) {
        float v = acc[nt][r] * invk + ((row0 + r == col) ? 1.0f : 0.0f);
        short h = f2b(v);
        hi[r] = h;
        lo[r] = f2b(v - b2f(h));
      }
      *(s4v*)(RThi + col * 136 + row0) = hi;
      *(s4v*)(RTlo + col * 136 + row0) = lo;
    }
    __syncthreads();
  }

  for (int it = 0; it < jsq; ++it) {
    s8v Shi[4], Slo[4];
#pragma unroll
    for (int ks = 0; ks < 4; ++ks) {
      int m = mr + c_;
      int k0 = ks * 32 + g_ * 8;
#pragma unroll
      for (int i = 0; i < 8; ++i) {
        Shi[ks][i] = RThi[(k0 + i) * 136 + m];
        Slo[ks][i] = RTlo[(k0 + i) * 136 + m];
      }
    }
    f4v acc[8];
#pragma unroll
    for (int nt = 0; nt < 8; ++nt) acc[nt] = (f4v){0.f, 0.f, 0.f, 0.f};
#pragma unroll
    for (int ks = 0; ks < 4; ++ks) {
#pragma unroll
      for (int nt = 0; nt < 8; ++nt) {
        s8v bh = ldfrag(RThi, nt * 16, ks * 32, 136);
        s8v bl = ldfrag(RTlo, nt * 16, ks * 32, 136);
        acc[nt] = MFMA(Shi[ks], bh, acc[nt]);
        acc[nt] = MFMA(Slo[ks], bh, acc[nt]);
        acc[nt] = MFMA(Shi[ks], bl, acc[nt]);
      }
    }
    __syncthreads();
    const int row0 = mr + g_ * 4;
#pragma unroll
    for (int nt = 0; nt < 8; ++nt) {
      const int col = nt * 16 + c_;
      s4v hi, lo;
#pragma unroll
      for (int r = 0; r < 4; ++r) {
        float v = acc[nt][r];
        short h = f2b(v);
        hi[r] = h;
        lo[r] = f2b(v - b2f(h));
      }
      *(s4v*)(RThi + col * 136 + row0) = hi;
      *(s4v*)(RTlo + col * 136 + row0) = lo;
    }
    __syncthreads();
  }

  // ---- W2K = K @ phi_W2 (accs in regs; reads RT + raw sW2) ----
  f4v acc[6];
  {
    s8v Shi[4], Slo[4];
#pragma unroll
    for (int ks = 0; ks < 4; ++ks) {
      int m = mr + c_;
      int k0 = ks * 32 + g_ * 8;
#pragma unroll
      for (int i = 0; i < 8; ++i) {
        Shi[ks][i] = RThi[(k0 + i) * 136 + m];
        Slo[ks][i] = RTlo[(k0 + i) * 136 + m];
      }
    }
#pragma unroll
    for (int nt = 0; nt < 6; ++nt) acc[nt] = (f4v){0.f, 0.f, 0.f, 0.f};
#pragma unroll
    for (int ks = 0; ks < 4; ++ks) {
#pragma unroll
      for (int nt = 0; nt < 6; ++nt) {
        s8v bh, bl;
#pragma unroll
        for (int i = 0; i < 8; ++i) {
          float v = sW2[(ks * 32 + g_ * 8 + i) * 96 + nt * 16 + c_];
          short h = f2b(v);
          bh[i] = h;
          bl[i] = f2b(v - b2f(h));
        }
        acc[nt] = MFMA(Shi[ks], bh, acc[nt]);
        acc[nt] = MFMA(Slo[ks], bh, acc[nt]);
        acc[nt] = MFMA(Shi[ks], bl, acc[nt]);
      }
    }
  }
  __syncthreads();   // all raw-sW2 reads complete -> region reusable

  // ---- M1 + W2K: scatter into sW2-region staging, coalesced copy out ----
  short* m1st = (short*)sW2;        // 8192 shorts (16KB)
  short* w2st = m1st + 8192;        // 12288 shorts (24KB)
  for (int e = tid; e < 8192; e += 512) {
    int n = e >> 6, kk = e & 63;
    float v = b2f(RThi[kk * 136 + n]) + b2f(RTlo[kk * 136 + n]);
    m1st[fragidx(n, kk, 2)] = f2b(v);
  }
#pragma unroll
  for (int nt = 0; nt < 6; ++nt)
#pragma unroll
    for (int r = 0; r < 4; ++r)
      w2st[fragidx(mr + g_ * 4 + r, phinv(nt * 16 + c_), 3)] = f2b(acc[nt][r]);
  __syncthreads();
  for (int i = tid; i < 1024; i += 512)
    ((f4v*)(wsp + WS_M1))[i] = ((const f4v*)m1st)[i];
  for (int i = tid; i < 1536; i += 512)
    ((f4v*)(wsp + WS_W2K))[i] = ((const f4v*)w2st)[i];
}

// ---------------------------------------------------------------------------
// Kernel 2: 16-WAVE fully-fused chain. 1024 threads (16 waves = 4 waves/EU,
// double r16's TLP) — legal because the fused per-16-row chain runs in 48
// VGPRs (r17-measured) < the 64-reg clamp of 1024-thread blocks (r13).
// ALL weights in LDS (91KB, 1 block/CU) — fixes r17's global-weight L1-miss.
// Z in registers (zbw 16). Microtile = 16 rows, 8 per wave.
// Zero in-loop barriers; all LDS lane-linear conflict-free b128.
// ---------------------------------------------------------------------------
__global__ __launch_bounds__(1024, 4) void koop_main(
    const float* __restrict__ xg, const float* __restrict__ b1g,
    const float* __restrict__ bi1g, const float* __restrict__ bi2g,
    const short* __restrict__ wsp, float* __restrict__ outg) {
  extern __shared__ __align__(16) char smem[];
  short* sW = (short*)smem;                  // 45056 shorts = 90112 B
  float* sB = (float*)(smem + 90112);        // b1[96] bi1[96] bi2[64]

  const int tid = threadIdx.x, lane = tid & 63, wid = tid >> 6;
  const int c_ = lane & 15, g_ = lane >> 4;

  for (int i = tid; i < 45056 / 8; i += 1024)
    ((f4v*)sW)[i] = ((const f4v*)wsp)[i];
  if (tid < 96) sB[tid] = b1g[tid];
  else if (tid < 192) sB[tid] = bi1g[tid - 96];
  else if (tid < 256) sB[tid] = bi2g[tid - 192];
  __syncthreads();   // the only barrier

  const short* wM1  = sW + WS_M1;
  const short* wI1  = sW + WS_I1;
  const short* wW1  = sW + WS_W1;
  const short* wW2K = sW + WS_W2K;
  const short* wI2  = sW + WS_I2;

  const int w = blockIdx.x * 16 + wid;       // 0..4095

  for (int mt = w; mt < NMT; mt += NWAVE) {
    const size_t r0 = (size_t)mt * 16;

    // ---- X: global -> regs -> bf16 B-frags (8 regs) ----
    s8v bx[2];
#pragma unroll
    for (int ks = 0; ks < 2; ++ks) {
      const float* p = xg + (r0 + c_) * 64 + ks * 32 + g_ * 8;
      bx[ks] = pack8(*(const f4v*)p, *(const f4v*)(p + 4));
    }

    // ---- stage 1: H = relu(W1 . X^T + b1) -> hbw[3] ----
    u32x4 hbw[3];
#pragma unroll
    for (int fb = 0; fb < 6; ++fb) {
      s8v w0 = ldw(wW1, fb * 2 + 0), w1 = ldw(wW1, fb * 2 + 1);
      f4v bias = *(const f4v*)(sB + fb * 16 + g_ * 4);
      f4v a = bias;
      a = MFMA(w0, bx[0], a);
      a = MFMA(w1, bx[1], a);
      hbw[fb >> 1][(fb & 1) * 2 + 0] = pk2r(a[0], a[1]);
      hbw[fb >> 1][(fb & 1) * 2 + 1] = pk2r(a[2], a[3]);
    }

    // ---- stage 2: Z = M1 . X^T + W2K . H^T -> zbw[4] ----
    u32x4 zbw[4];
#pragma unroll
    for (int fb = 0; fb < 8; ++fb) {
      s8v m0 = ldw(wM1, fb * 2 + 0), m1 = ldw(wM1, fb * 2 + 1);
      s8v k0 = ldw(wW2K, fb * 3 + 0), k1 = ldw(wW2K, fb * 3 + 1), k2 = ldw(wW2K, fb * 3 + 2);
      f4v a = (f4v){0.f, 0.f, 0.f, 0.f};
      a = MFMA(m0, bx[0], a);
      a = MFMA(m1, bx[1], a);
      a = MFMA(k0, BCV(hbw[0]), a);
      a = MFMA(k1, BCV(hbw[1]), a);
      a = MFMA(k2, BCV(hbw[2]), a);
      zbw[fb >> 1][(fb & 1) * 2 + 0] = pk2(a[0], a[1]);
      zbw[fb >> 1][(fb & 1) * 2 + 1] = pk2(a[2], a[3]);
    }

    // ---- stage 3: H2 = relu(I1 . Z^T + bi1) -> h2w[3] ----
    u32x4 h2w[3];
#pragma unroll
    for (int fb = 0; fb < 6; ++fb) {
      s8v i0 = ldw(wI1, fb * 4 + 0), i1 = ldw(wI1, fb * 4 + 1);
      s8v i2 = ldw(wI1, fb * 4 + 2), i3 = ldw(wI1, fb * 4 + 3);
      f4v bias = *(const f4v*)(sB + 96 + fb * 16 + g_ * 4);
      f4v a = bias;
      a = MFMA(i0, BCV(zbw[0]), a);
      a = MFMA(i1, BCV(zbw[1]), a);
      a = MFMA(i2, BCV(zbw[2]), a);
      a = MFMA(i3, BCV(zbw[3]), a);
      h2w[fb >> 1][(fb & 1) * 2 + 0] = pk2r(a[0], a[1]);
      h2w[fb >> 1][(fb & 1) * 2 + 1] = pk2r(a[2], a[3]);
    }

    // ---- stage 4: OUT = I2 . H2^T + bi2 -> global (16B/lane) ----
#pragma unroll
    for (int fb = 0; fb < 4; ++fb) {
      s8v j0 = ldw(wI2, fb * 3 + 0), j1 = ldw(wI2, fb * 3 + 1), j2 = ldw(wI2, fb * 3 + 2);
      f4v bias = *(const f4v*)(sB + 192 + fb * 16 + g_ * 4);
      f4v a = bias;
      a = MFMA(j0, BCV(h2w[0]), a);
      a = MFMA(j1, BCV(h2w[1]), a);
      a = MFMA(j2, BCV(h2w[2]), a);
      *(f4v*)(outg + (r0 + c_) * 64 + fb * 16 + g_ * 4) = a;
    }
  }
}

#define PREP_LDS (128 * 136 * 2 * 2 + 128 * 96 * 4 + 130 * 4)   // 119304 B
#define MAIN_LDS (90112 + 1024)                                  // 91136 B

extern "C" void kernel_launch(void* const* d_in, const int* in_sizes, int n_in,
                              void* d_out, int out_size, void* d_ws, size_t ws_size,
                              hipStream_t stream) {
  (void)in_sizes; (void)n_in; (void)out_size; (void)ws_size;
  const float* t     = (const float*)d_in[0];
  const float* x     = (const float*)d_in[1];
  const float* A     = (const float*)d_in[2];
  const float* phiW1 = (const float*)d_in[3];
  const float* phib1 = (const float*)d_in[4];
  const float* phiW2 = (const float*)d_in[5];
  const float* invW1 = (const float*)d_in[6];
  const float* invb1 = (const float*)d_in[7];
  const float* invW2 = (const float*)d_in[8];
  const float* invb2 = (const float*)d_in[9];
  float* out = (float*)d_out;
  short* wsp = (short*)d_ws;

  (void)hipFuncSetAttribute((const void*)koop_prep,
                            hipFuncAttributeMaxDynamicSharedMemorySize, PREP_LDS);
  (void)hipFuncSetAttribute((const void*)koop_main,
                            hipFuncAttributeMaxDynamicSharedMemorySize, MAIN_LDS);

  koop_prep<<<1, 512, PREP_LDS, stream>>>(t, A, phiW2, phiW1, invW1, invW2, wsp);
  koop_main<<<256, 1024, MAIN_LDS, stream>>>(x, phib1, invb1, invb2, wsp, out);
}

// Round 19
// 590.998 us; speedup vs baseline: 1.2300x; 1.2300x over previous
//
#include <hip/hip_runtime.h>

#define BTOT    524288
#define NMT     32768          // 16-row microtiles
#define NWAVE   3072           // 256 blocks x 12 waves
#define TN      6              // Taylor order for expm (theta<=1 -> rem ~2.2e-4)

typedef __attribute__((ext_vector_type(8))) short s8v;     // 8 x bf16 bits
typedef __attribute__((ext_vector_type(4))) short s4v;     // 4 x bf16 bits (b64)
typedef __attribute__((ext_vector_type(4))) float f4v;
typedef __attribute__((ext_vector_type(4))) unsigned u32x4;

#define MFMA(a,b,c) __builtin_amdgcn_mfma_f32_16x16x32_bf16((a),(b),(c),0,0,0)
#define BCV(x) __builtin_bit_cast(s8v, x)

__device__ __forceinline__ short f2b(float f) {            // f32 -> bf16 (RNE)
  union { float f; unsigned u; } v; v.f = f;
  unsigned r = v.u + 0x7fffu + ((v.u >> 16) & 1u);
  return (short)(r >> 16);
}
__device__ __forceinline__ float b2f(short s) {
  union { float f; unsigned u; } v; v.u = ((unsigned)(unsigned short)s) << 16;
  return v.f;
}
__device__ __forceinline__ unsigned bfb(float f) {         // bf16 bits in low16
  union { float f; unsigned u; } v; v.f = f;
  return (v.u + 0x7fffu + ((v.u >> 16) & 1u)) >> 16;
}
// packed pair, round-half-up (<=0.5 ulp): 2 adds + 1 v_perm_b32 (r12-proven)
__device__ __forceinline__ unsigned pk2(float a, float b) {
#if __has_builtin(__builtin_amdgcn_perm)
  unsigned ua = __builtin_bit_cast(unsigned, a) + 0x8000u;
  unsigned ub = __builtin_bit_cast(unsigned, b) + 0x8000u;
  return __builtin_amdgcn_perm(ub, ua, 0x07060302u);   // {hi16(ub), hi16(ua)}
#else
  return bfb(a) | (bfb(b) << 16);
#endif
}
__device__ __forceinline__ unsigned pk2r(float a, float b) { return pk2(fmaxf(a,0.f), fmaxf(b,0.f)); }
__device__ __forceinline__ s8v pack8(f4v u, f4v v) {
  u32x4 w = {pk2(u[0],u[1]), pk2(u[2],u[3]), pk2(v[0],v[1]), pk2(v[2],v[3])};
  return BCV(w);
}

// prep-only: MFMA fragment load from padded row-major LDS tile
__device__ __forceinline__ s8v ldfrag(const short* base, int row0, int kbase, int stride) {
  const int l = threadIdx.x & 63;
  return *(const s8v*)(base + (row0 + (l & 15)) * stride + kbase + (l >> 4) * 8);
}
// frag-linear chunk read: lane-linear 16B -> conflict-free
__device__ __forceinline__ s8v ldw(const short* base, int chunk) {
  return *(const s8v*)(base + (chunk * 64 + (threadIdx.x & 63)) * 8);
}

// ---- ws layout (shorts): fragment-linear packed weights ----
#define WS_M1   0        // [128][64]  KS=2  (k natural: X)
#define WS_I1   8192     // [96][128]  KS=4  (k phinv:   Z)
#define WS_W1   20480    // [96][64]   KS=2  (k natural: X)
#define WS_W2K  26624    // [128][96]  KS=3  (k phinv:   H)
#define WS_I2   38912    // [64][96]   KS=3  (k phinv:   H2)

__device__ __forceinline__ int fragidx(int n, int k, int KS) {
  int jj = n >> 4, ks = k >> 5;
  int l = (n & 15) | (((k >> 3) & 3) << 4);
  return ((jj * KS + ks) * 64 + l) * 8 + (k & 7);
}
// feature-index permutation absorbing D-frag->B-frag layout: swap bit4 <-> bits3:2
__device__ __forceinline__ int phinv(int f) {
  return (f & ~31) | (((f >> 2) & 3) << 3) | (((f >> 4) & 1) << 2) | (f & 3);
}

// ---------------------------------------------------------------------------
// Kernel 1: expm(A*t/24) via scaling+squaring Taylor (split-bf16 MFMA), then
// emit ALL weights as bf16 fragment-linear buffers in ws. (r16 version —
// scatter->LDS staging->coalesced copy; validated)
// ---------------------------------------------------------------------------
__global__ __launch_bounds__(512, 2) void koop_prep(
    const float* __restrict__ tptr, const float* __restrict__ Ag,
    const float* __restrict__ W2g, const float* __restrict__ w1g,
    const float* __restrict__ i1g, const float* __restrict__ i2g,
    short* __restrict__ wsp) {
  extern __shared__ __align__(16) char smem[];
  short* RThi = (short*)smem;              // [128][136]
  short* RTlo = RThi + 128 * 136;          // [128][136]
  float* sW2  = (float*)(RTlo + 128 * 136);// [128][96]
  float* sred = sW2 + 128 * 96;            // [130]
  float* scratch = (float*)smem;           // [128][128] f32 alias
  short* pkst = RThi;                      // pack staging (pre-expm, 24KB max)

  const int tid = threadIdx.x;
  const int lane = tid & 63, wid = tid >> 6;
  const int c_ = lane & 15, g_ = lane >> 4;
  const int mr = wid * 16;

  // W2 raw staging (disjoint region, can run early)
  for (int i = tid; i < 128 * 96; i += 512) sW2[i] = W2g[i];

  // ---- raw-weight packing: scatter->LDS, coalesced copy->global ----
  for (int e = tid; e < 6144; e += 512)
    pkst[fragidx(e >> 6, e & 63, 2)] = f2b(w1g[e]);
  __syncthreads();
  for (int i = tid; i < 768; i += 512)
    ((f4v*)(wsp + WS_W1))[i] = ((const f4v*)pkst)[i];
  __syncthreads();
  for (int e = tid; e < 12288; e += 512)
    pkst[fragidx(e >> 7, phinv(e & 127), 4)] = f2b(i1g[e]);
  __syncthreads();
  for (int i = tid; i < 1536; i += 512)
    ((f4v*)(wsp + WS_I1))[i] = ((const f4v*)pkst)[i];
  __syncthreads();
  for (int e = tid; e < 6144; e += 512)
    pkst[fragidx(e / 96, phinv(e % 96), 3)] = f2b(i2g[e]);
  __syncthreads();
  for (int i = tid; i < 768; i += 512)
    ((f4v*)(wsp + WS_I2))[i] = ((const f4v*)pkst)[i];
  __syncthreads();

  const float s = tptr[0] * (1.0f / 24.0f);
  for (int i = tid; i < 128 * 128; i += 512) scratch[i] = Ag[i] * s;
  __syncthreads();

  {  // inf-norm: 4 threads/row, shuffle-reduce
    const int row = tid >> 2, q = tid & 3;
    float su = 0.f;
    const float* rp = scratch + row * 128 + q * 32;
#pragma unroll 8
    for (int j = 0; j < 32; ++j) su += fabsf(rp[j]);
    su += __shfl_xor(su, 1);
    su += __shfl_xor(su, 2);
    if (q == 0) sred[row] = su;
  }
  __syncthreads();
  if (tid < 64) {
    float m = fmaxf(sred[tid], sred[tid + 64]);
#pragma unroll
    for (int d = 32; d; d >>= 1) m = fmaxf(m, __shfl_xor(m, d));
    if (tid == 0) {
      int j = 0;
      if (m > 1.0f) {
        j = (int)ceilf(log2f(m));
        if (j < 0) j = 0; if (j > 20) j = 20;
      }
      sred[128] = (float)j; sred[129] = exp2f(-(float)j);
    }
  }
  __syncthreads();
  const int jsq = (int)sred[128];
  const float sc = sred[129];

  s8v Ahi[4], Alo[4];
#pragma unroll
  for (int ks = 0; ks < 4; ++ks) {
    const float* p = scratch + (mr + c_) * 128 + ks * 32 + g_ * 8;
    f4v u = *(const f4v*)p, v = *(const f4v*)(p + 4);
    float vals[8] = {u[0], u[1], u[2], u[3], v[0], v[1], v[2], v[3]};
#pragma unroll
    for (int i = 0; i < 8; ++i) {
      float y = vals[i] * sc;
      short h = f2b(y);
      Ahi[ks][i] = h;
      Alo[ks][i] = f2b(y - b2f(h));
    }
  }
  float yv[32];
#pragma unroll
  for (int e = 0; e < 32; ++e) yv[e] = scratch[tid * 32 + e];
  __syncthreads();

#pragma unroll
  for (int e = 0; e < 32; ++e) {
    int idx = tid * 32 + e;
    int r = idx >> 7, c = idx & 127;
    float v = yv[e] * sc * (1.0f / TN) + ((r == c) ? 1.0f : 0.0f);
    short h = f2b(v);
    RThi[c * 136 + r] = h;
    RTlo[c * 136 + r] = f2b(v - b2f(h));
  }
  __syncthreads();

  for (int k = TN - 1; k >= 1; --k) {
    f4v acc[8];
#pragma unroll
    for (int nt = 0; nt < 8; ++nt) acc[nt] = (f4v){0.f, 0.f, 0.f, 0.f};
#pragma unroll
    for (int ks = 0; ks < 4; ++ks) {
#pragma unroll
      for (int nt = 0; nt < 8; ++nt) {
        s8v bh = ldfrag(RThi, nt * 16, ks * 32, 136);
        s8v bl = ldfrag(RTlo, nt * 16, ks * 32, 136);
        acc[nt] = MFMA(Ahi[ks], bh, acc[nt]);
        acc[nt] = MFMA(Alo[ks], bh, acc[nt]);
        acc[nt] = MFMA(Ahi[ks], bl, acc[nt]);
      }
    }
    __syncthreads();
    const float invk = 1.0f / (float)k;
    const int row0 = mr + g_ * 4;
#pragma unroll
    for (int nt = 0; nt < 8; ++nt) {
      const int col = nt * 16 + c_;
      s4v hi, lo;
#pragma unroll
      for (int r = 0; r < 4; ++r) {
        float v = acc[nt][r] * invk + ((row0 + r == col) ? 1.0f : 0.0f);
        short h = f2b(v);
        hi[r] = h;
        lo[r] = f2b(v - b2f(h));
      }
      *(s4v*)(RThi + col * 136 + row0) = hi;
      *(s4v*)(RTlo + col * 136 + row0) = lo;
    }
    __syncthreads();
  }

  for (int it = 0; it < jsq; ++it) {
    s8v Shi[4], Slo[4];
#pragma unroll
    for (int ks = 0; ks < 4; ++ks) {
      int m = mr + c_;
      int k0 = ks * 32 + g_ * 8;
#pragma unroll
      for (int i = 0; i < 8; ++i) {
        Shi[ks][i] = RThi[(k0 + i) * 136 + m];
        Slo[ks][i] = RTlo[(k0 + i) * 136 + m];
      }
    }
    f4v acc[8];
#pragma unroll
    for (int nt = 0; nt < 8; ++nt) acc[nt] = (f4v){0.f, 0.f, 0.f, 0.f};
#pragma unroll
    for (int ks = 0; ks < 4; ++ks) {
#pragma unroll
      for (int nt = 0; nt < 8; ++nt) {
        s8v bh = ldfrag(RThi, nt * 16, ks * 32, 136);
        s8v bl = ldfrag(RTlo, nt * 16, ks * 32, 136);
        acc[nt] = MFMA(Shi[ks], bh, acc[nt]);
        acc[nt] = MFMA(Slo[ks], bh, acc[nt]);
        acc[nt] = MFMA(Shi[ks], bl, acc[nt]);
      }
    }
    __syncthreads();
    const int row0 = mr + g_ * 4;
#pragma unroll
    for (int nt = 0; nt < 8; ++nt) {
      const int col = nt * 16 + c_;
      s4v hi, lo;
#pragma unroll
      for (int r = 0; r < 4; ++r) {
        float v = acc[nt][r];
        short h = f2b(v);
        hi[r] = h;
        lo[r] = f2b(v - b2f(h));
      }
      *(s4v*)(RThi + col * 136 + row0) = hi;
      *(s4v*)(RTlo + col * 136 + row0) = lo;
    }
    __syncthreads();
  }

  // ---- W2K = K @ phi_W2 (accs in regs; reads RT + raw sW2) ----
  f4v acc[6];
  {
    s8v Shi[4], Slo[4];
#pragma unroll
    for (int ks = 0; ks < 4; ++ks) {
      int m = mr + c_;
      int k0 = ks * 32 + g_ * 8;
#pragma unroll
      for (int i = 0; i < 8; ++i) {
        Shi[ks][i] = RThi[(k0 + i) * 136 + m];
        Slo[ks][i] = RTlo[(k0 + i) * 136 + m];
      }
    }
#pragma unroll
    for (int nt = 0; nt < 6; ++nt) acc[nt] = (f4v){0.f, 0.f, 0.f, 0.f};
#pragma unroll
    for (int ks = 0; ks < 4; ++ks) {
#pragma unroll
      for (int nt = 0; nt < 6; ++nt) {
        s8v bh, bl;
#pragma unroll
        for (int i = 0; i < 8; ++i) {
          float v = sW2[(ks * 32 + g_ * 8 + i) * 96 + nt * 16 + c_];
          short h = f2b(v);
          bh[i] = h;
          bl[i] = f2b(v - b2f(h));
        }
        acc[nt] = MFMA(Shi[ks], bh, acc[nt]);
        acc[nt] = MFMA(Slo[ks], bh, acc[nt]);
        acc[nt] = MFMA(Shi[ks], bl, acc[nt]);
      }
    }
  }
  __syncthreads();   // all raw-sW2 reads complete -> region reusable

  // ---- M1 + W2K: scatter into sW2-region staging, coalesced copy out ----
  short* m1st = (short*)sW2;        // 8192 shorts (16KB)
  short* w2st = m1st + 8192;        // 12288 shorts (24KB)
  for (int e = tid; e < 8192; e += 512) {
    int n = e >> 6, kk = e & 63;
    float v = b2f(RThi[kk * 136 + n]) + b2f(RTlo[kk * 136 + n]);
    m1st[fragidx(n, kk, 2)] = f2b(v);
  }
#pragma unroll
  for (int nt = 0; nt < 6; ++nt)
#pragma unroll
    for (int r = 0; r < 4; ++r)
      w2st[fragidx(mr + g_ * 4 + r, phinv(nt * 16 + c_), 3)] = f2b(acc[nt][r]);
  __syncthreads();
  for (int i = tid; i < 1024; i += 512)
    ((f4v*)(wsp + WS_M1))[i] = ((const f4v*)m1st)[i];
  for (int i = tid; i < 1536; i += 512)
    ((f4v*)(wsp + WS_W2K))[i] = ((const f4v*)w2st)[i];
}

// ---------------------------------------------------------------------------
// Kernel 2: 12-WAVE fully-fused chain. 768 threads = 12 waves = 3 waves/EU
// (1.5x r16's TLP). Register clamp at 768 thr ~ 512/3 = 170 (allocator
// targets 2 blocks/CU: 512thr->128, 1024thr->64 measured) >> the ~75 the
// fused chain needs — unlike r18's 1024-thr/64-cap spill. ALL weights in LDS
// (91KB, 1 block/CU). Z in registers. Microtile = 16 rows.
// Zero in-loop barriers; all LDS lane-linear conflict-free b128.
// ---------------------------------------------------------------------------
__global__ __launch_bounds__(768, 3) void koop_main(
    const float* __restrict__ xg, const float* __restrict__ b1g,
    const float* __restrict__ bi1g, const float* __restrict__ bi2g,
    const short* __restrict__ wsp, float* __restrict__ outg) {
  extern __shared__ __align__(16) char smem[];
  short* sW = (short*)smem;                  // 45056 shorts = 90112 B
  float* sB = (float*)(smem + 90112);        // b1[96] bi1[96] bi2[64]

  const int tid = threadIdx.x, lane = tid & 63, wid = tid >> 6;
  const int c_ = lane & 15, g_ = lane >> 4;

  for (int i = tid; i < 45056 / 8; i += 768)
    ((f4v*)sW)[i] = ((const f4v*)wsp)[i];
  if (tid < 96) sB[tid] = b1g[tid];
  else if (tid < 192) sB[tid] = bi1g[tid - 96];
  else if (tid < 256) sB[tid] = bi2g[tid - 192];
  __syncthreads();   // the only barrier

  const short* wM1  = sW + WS_M1;
  const short* wI1  = sW + WS_I1;
  const short* wW1  = sW + WS_W1;
  const short* wW2K = sW + WS_W2K;
  const short* wI2  = sW + WS_I2;

  const int w = blockIdx.x * 12 + wid;       // 0..3071

  for (int mt = w; mt < NMT; mt += NWAVE) {
    const size_t r0 = (size_t)mt * 16;

    // ---- X: global -> regs -> bf16 B-frags (8 regs) ----
    s8v bx[2];
#pragma unroll
    for (int ks = 0; ks < 2; ++ks) {
      const float* p = xg + (r0 + c_) * 64 + ks * 32 + g_ * 8;
      bx[ks] = pack8(*(const f4v*)p, *(const f4v*)(p + 4));
    }

    // ---- stage 1: H = relu(W1 . X^T + b1) -> hbw[3] ----
    u32x4 hbw[3];
#pragma unroll
    for (int fb = 0; fb < 6; ++fb) {
      s8v w0 = ldw(wW1, fb * 2 + 0), w1 = ldw(wW1, fb * 2 + 1);
      f4v bias = *(const f4v*)(sB + fb * 16 + g_ * 4);
      f4v a = bias;
      a = MFMA(w0, bx[0], a);
      a = MFMA(w1, bx[1], a);
      hbw[fb >> 1][(fb & 1) * 2 + 0] = pk2r(a[0], a[1]);
      hbw[fb >> 1][(fb & 1) * 2 + 1] = pk2r(a[2], a[3]);
    }

    // ---- stage 2: Z = M1 . X^T + W2K . H^T -> zbw[4] ----
    u32x4 zbw[4];
#pragma unroll
    for (int fb = 0; fb < 8; ++fb) {
      s8v m0 = ldw(wM1, fb * 2 + 0), m1 = ldw(wM1, fb * 2 + 1);
      s8v k0 = ldw(wW2K, fb * 3 + 0), k1 = ldw(wW2K, fb * 3 + 1), k2 = ldw(wW2K, fb * 3 + 2);
      f4v a = (f4v){0.f, 0.f, 0.f, 0.f};
      a = MFMA(m0, bx[0], a);
      a = MFMA(m1, bx[1], a);
      a = MFMA(k0, BCV(hbw[0]), a);
      a = MFMA(k1, BCV(hbw[1]), a);
      a = MFMA(k2, BCV(hbw[2]), a);
      zbw[fb >> 1][(fb & 1) * 2 + 0] = pk2(a[0], a[1]);
      zbw[fb >> 1][(fb & 1) * 2 + 1] = pk2(a[2], a[3]);
    }

    // ---- stage 3: H2 = relu(I1 . Z^T + bi1) -> h2w[3] ----
    u32x4 h2w[3];
#pragma unroll
    for (int fb = 0; fb < 6; ++fb) {
      s8v i0 = ldw(wI1, fb * 4 + 0), i1 = ldw(wI1, fb * 4 + 1);
      s8v i2 = ldw(wI1, fb * 4 + 2), i3 = ldw(wI1, fb * 4 + 3);
      f4v bias = *(const f4v*)(sB + 96 + fb * 16 + g_ * 4);
      f4v a = bias;
      a = MFMA(i0, BCV(zbw[0]), a);
      a = MFMA(i1, BCV(zbw[1]), a);
      a = MFMA(i2, BCV(zbw[2]), a);
      a = MFMA(i3, BCV(zbw[3]), a);
      h2w[fb >> 1][(fb & 1) * 2 + 0] = pk2r(a[0], a[1]);
      h2w[fb >> 1][(fb & 1) * 2 + 1] = pk2r(a[2], a[3]);
    }

    // ---- stage 4: OUT = I2 . H2^T + bi2 -> global (16B/lane) ----
#pragma unroll
    for (int fb = 0; fb < 4; ++fb) {
      s8v j0 = ldw(wI2, fb * 3 + 0), j1 = ldw(wI2, fb * 3 + 1), j2 = ldw(wI2, fb * 3 + 2);
      f4v bias = *(const f4v*)(sB + 192 + fb * 16 + g_ * 4);
      f4v a = bias;
      a = MFMA(j0, BCV(h2w[0]), a);
      a = MFMA(j1, BCV(h2w[1]), a);
      a = MFMA(j2, BCV(h2w[2]), a);
      *(f4v*)(outg + (r0 + c_) * 64 + fb * 16 + g_ * 4) = a;
    }
  }
}

#define PREP_LDS (128 * 136 * 2 * 2 + 128 * 96 * 4 + 130 * 4)   // 119304 B
#define MAIN_LDS (90112 + 1024)                                  // 91136 B

extern "C" void kernel_launch(void* const* d_in, const int* in_sizes, int n_in,
                              void* d_out, int out_size, void* d_ws, size_t ws_size,
                              hipStream_t stream) {
  (void)in_sizes; (void)n_in; (void)out_size; (void)ws_size;
  const float* t     = (const float*)d_in[0];
  const float* x     = (const float*)d_in[1];
  const float* A     = (const float*)d_in[2];
  const float* phiW1 = (const float*)d_in[3];
  const float* phib1 = (const float*)d_in[4];
  const float* phiW2 = (const float*)d_in[5];
  const float* invW1 = (const float*)d_in[6];
  const float* invb1 = (const float*)d_in[7];
  const float* invW2 = (const float*)d_in[8];
  const float* invb2 = (const float*)d_in[9];
  float* out = (float*)d_out;
  short* wsp = (short*)d_ws;

  (void)hipFuncSetAttribute((const void*)koop_prep,
                            hipFuncAttributeMaxDynamicSharedMemorySize, PREP_LDS);
  (void)hipFuncSetAttribute((const void*)koop_main,
                            hipFuncAttributeMaxDynamicSharedMemorySize, MAIN_LDS);

  koop_prep<<<1, 512, PREP_LDS, stream>>>(t, A, phiW2, phiW1, invW1, invW2, wsp);
  koop_main<<<256, 768, MAIN_LDS, stream>>>(x, phib1, invb1, invb2, wsp, out);
}

// Round 20
// 120.371 us; speedup vs baseline: 6.0389x; 4.9098x over previous
//
#include <hip/hip_runtime.h>

#define BTOT    524288
#define NMT     16384          // 32-row microtiles
#define NWAVE   2048           // 256 blocks x 8 waves
#define TN      6              // Taylor order for expm (theta<=1 -> rem ~2.2e-4)

typedef __attribute__((ext_vector_type(8))) short s8v;     // 8 x bf16 bits
typedef __attribute__((ext_vector_type(4))) short s4v;     // 4 x bf16 bits (b64)
typedef __attribute__((ext_vector_type(4))) float f4v;
typedef __attribute__((ext_vector_type(4))) unsigned u32x4;

#define MFMA(a,b,c) __builtin_amdgcn_mfma_f32_16x16x32_bf16((a),(b),(c),0,0,0)
#define BCV(x) __builtin_bit_cast(s8v, x)

__device__ __forceinline__ short f2b(float f) {            // f32 -> bf16 (RNE)
  union { float f; unsigned u; } v; v.f = f;
  unsigned r = v.u + 0x7fffu + ((v.u >> 16) & 1u);
  return (short)(r >> 16);
}
__device__ __forceinline__ float b2f(short s) {
  union { float f; unsigned u; } v; v.u = ((unsigned)(unsigned short)s) << 16;
  return v.f;
}
__device__ __forceinline__ unsigned bfb(float f) {         // bf16 bits in low16
  union { float f; unsigned u; } v; v.f = f;
  return (v.u + 0x7fffu + ((v.u >> 16) & 1u)) >> 16;
}
// packed pair, round-half-up (<=0.5 ulp): 2 adds + 1 v_perm_b32 (r12-proven)
__device__ __forceinline__ unsigned pk2(float a, float b) {
#if __has_builtin(__builtin_amdgcn_perm)
  unsigned ua = __builtin_bit_cast(unsigned, a) + 0x8000u;
  unsigned ub = __builtin_bit_cast(unsigned, b) + 0x8000u;
  return __builtin_amdgcn_perm(ub, ua, 0x07060302u);   // {hi16(ub), hi16(ua)}
#else
  return bfb(a) | (bfb(b) << 16);
#endif
}
__device__ __forceinline__ unsigned pk2r(float a, float b) { return pk2(fmaxf(a,0.f), fmaxf(b,0.f)); }
__device__ __forceinline__ s8v pack8(f4v u, f4v v) {
  u32x4 w = {pk2(u[0],u[1]), pk2(u[2],u[3]), pk2(v[0],v[1]), pk2(v[2],v[3])};
  return BCV(w);
}

// prep-only: MFMA fragment load from padded row-major LDS tile
__device__ __forceinline__ s8v ldfrag(const short* base, int row0, int kbase, int stride) {
  const int l = threadIdx.x & 63;
  return *(const s8v*)(base + (row0 + (l & 15)) * stride + kbase + (l >> 4) * 8);
}
// frag-linear chunk read: lane-linear 16B -> conflict-free
__device__ __forceinline__ s8v ldw(const short* base, int chunk) {
  return *(const s8v*)(base + (chunk * 64 + (threadIdx.x & 63)) * 8);
}

// ---- ws layout (shorts): fragment-linear packed weights ----
#define WS_M1   0        // [128][64]  KS=2  (k natural: X)
#define WS_I1   8192     // [96][128]  KS=4  (k phinv:   Z)
#define WS_W1   20480    // [96][64]   KS=2  (k natural: X)
#define WS_W2K  26624    // [128][96]  KS=3  (k phinv:   H)
#define WS_I2   38912    // [64][96]   KS=3  (k phinv:   H2)

__device__ __forceinline__ int fragidx(int n, int k, int KS) {
  int jj = n >> 4, ks = k >> 5;
  int l = (n & 15) | (((k >> 3) & 3) << 4);
  return ((jj * KS + ks) * 64 + l) * 8 + (k & 7);
}
// feature-index permutation absorbing D-frag->B-frag layout: swap bit4 <-> bits3:2
__device__ __forceinline__ int phinv(int f) {
  return (f & ~31) | (((f >> 2) & 3) << 3) | (((f >> 4) & 1) << 2) | (f & 3);
}

// ---------------------------------------------------------------------------
// Kernel 1: expm(A*t/24) via scaling+squaring Taylor (split-bf16 MFMA), then
// emit ALL weights as bf16 fragment-linear buffers in ws. (r16 version —
// scatter->LDS staging->coalesced copy; validated)
// ---------------------------------------------------------------------------
__global__ __launch_bounds__(512, 2) void koop_prep(
    const float* __restrict__ tptr, const float* __restrict__ Ag,
    const float* __restrict__ W2g, const float* __restrict__ w1g,
    const float* __restrict__ i1g, const float* __restrict__ i2g,
    short* __restrict__ wsp) {
  extern __shared__ __align__(16) char smem[];
  short* RThi = (short*)smem;              // [128][136]
  short* RTlo = RThi + 128 * 136;          // [128][136]
  float* sW2  = (float*)(RTlo + 128 * 136);// [128][96]
  float* sred = sW2 + 128 * 96;            // [130]
  float* scratch = (float*)smem;           // [128][128] f32 alias
  short* pkst = RThi;                      // pack staging (pre-expm, 24KB max)

  const int tid = threadIdx.x;
  const int lane = tid & 63, wid = tid >> 6;
  const int c_ = lane & 15, g_ = lane >> 4;
  const int mr = wid * 16;

  // W2 raw staging (disjoint region, can run early)
  for (int i = tid; i < 128 * 96; i += 512) sW2[i] = W2g[i];

  // ---- raw-weight packing: scatter->LDS, coalesced copy->global ----
  for (int e = tid; e < 6144; e += 512)
    pkst[fragidx(e >> 6, e & 63, 2)] = f2b(w1g[e]);
  __syncthreads();
  for (int i = tid; i < 768; i += 512)
    ((f4v*)(wsp + WS_W1))[i] = ((const f4v*)pkst)[i];
  __syncthreads();
  for (int e = tid; e < 12288; e += 512)
    pkst[fragidx(e >> 7, phinv(e & 127), 4)] = f2b(i1g[e]);
  __syncthreads();
  for (int i = tid; i < 1536; i += 512)
    ((f4v*)(wsp + WS_I1))[i] = ((const f4v*)pkst)[i];
  __syncthreads();
  for (int e = tid; e < 6144; e += 512)
    pkst[fragidx(e / 96, phinv(e % 96), 3)] = f2b(i2g[e]);
  __syncthreads();
  for (int i = tid; i < 768; i += 512)
    ((f4v*)(wsp + WS_I2))[i] = ((const f4v*)pkst)[i];
  __syncthreads();

  const float s = tptr[0] * (1.0f / 24.0f);
  for (int i = tid; i < 128 * 128; i += 512) scratch[i] = Ag[i] * s;
  __syncthreads();

  {  // inf-norm: 4 threads/row, shuffle-reduce
    const int row = tid >> 2, q = tid & 3;
    float su = 0.f;
    const float* rp = scratch + row * 128 + q * 32;
#pragma unroll 8
    for (int j = 0; j < 32; ++j) su += fabsf(rp[j]);
    su += __shfl_xor(su, 1);
    su += __shfl_xor(su, 2);
    if (q == 0) sred[row] = su;
  }
  __syncthreads();
  if (tid < 64) {
    float m = fmaxf(sred[tid], sred[tid + 64]);
#pragma unroll
    for (int d = 32; d; d >>= 1) m = fmaxf(m, __shfl_xor(m, d));
    if (tid == 0) {
      int j = 0;
      if (m > 1.0f) {
        j = (int)ceilf(log2f(m));
        if (j < 0) j = 0; if (j > 20) j = 20;
      }
      sred[128] = (float)j; sred[129] = exp2f(-(float)j);
    }
  }
  __syncthreads();
  const int jsq = (int)sred[128];
  const float sc = sred[129];

  s8v Ahi[4], Alo[4];
#pragma unroll
  for (int ks = 0; ks < 4; ++ks) {
    const float* p = scratch + (mr + c_) * 128 + ks * 32 + g_ * 8;
    f4v u = *(const f4v*)p, v = *(const f4v*)(p + 4);
    float vals[8] = {u[0], u[1], u[2], u[3], v[0], v[1], v[2], v[3]};
#pragma unroll
    for (int i = 0; i < 8; ++i) {
      float y = vals[i] * sc;
      short h = f2b(y);
      Ahi[ks][i] = h;
      Alo[ks][i] = f2b(y - b2f(h));
    }
  }
  float yv[32];
#pragma unroll
  for (int e = 0; e < 32; ++e) yv[e] = scratch[tid * 32 + e];
  __syncthreads();

#pragma unroll
  for (int e = 0; e < 32; ++e) {
    int idx = tid * 32 + e;
    int r = idx >> 7, c = idx & 127;
    float v = yv[e] * sc * (1.0f / TN) + ((r == c) ? 1.0f : 0.0f);
    short h = f2b(v);
    RThi[c * 136 + r] = h;
    RTlo[c * 136 + r] = f2b(v - b2f(h));
  }
  __syncthreads();

  for (int k = TN - 1; k >= 1; --k) {
    f4v acc[8];
#pragma unroll
    for (int nt = 0; nt < 8; ++nt) acc[nt] = (f4v){0.f, 0.f, 0.f, 0.f};
#pragma unroll
    for (int ks = 0; ks < 4; ++ks) {
#pragma unroll
      for (int nt = 0; nt < 8; ++nt) {
        s8v bh = ldfrag(RThi, nt * 16, ks * 32, 136);
        s8v bl = ldfrag(RTlo, nt * 16, ks * 32, 136);
        acc[nt] = MFMA(Ahi[ks], bh, acc[nt]);
        acc[nt] = MFMA(Alo[ks], bh, acc[nt]);
        acc[nt] = MFMA(Ahi[ks], bl, acc[nt]);
      }
    }
    __syncthreads();
    const float invk = 1.0f / (float)k;
    const int row0 = mr + g_ * 4;
#pragma unroll
    for (int nt = 0; nt < 8; ++nt) {
      const int col = nt * 16 + c_;
      s4v hi, lo;
#pragma unroll
      for (int r = 0; r < 4; ++r) {
        float v = acc[nt][r] * invk + ((row0 + r == col) ? 1.0f : 0.0f);
        short h = f2b(v);
        hi[r] = h;
        lo[r] = f2b(v - b2f(h));
      }
      *(s4v*)(RThi + col * 136 + row0) = hi;
      *(s4v*)(RTlo + col * 136 + row0) = lo;
    }
    __syncthreads();
  }

  for (int it = 0; it < jsq; ++it) {
    s8v Shi[4], Slo[4];
#pragma unroll
    for (int ks = 0; ks < 4; ++ks) {
      int m = mr + c_;
      int k0 = ks * 32 + g_ * 8;
#pragma unroll
      for (int i = 0; i < 8; ++i) {
        Shi[ks][i] = RThi[(k0 + i) * 136 + m];
        Slo[ks][i] = RTlo[(k0 + i) * 136 + m];
      }
    }
    f4v acc[8];
#pragma unroll
    for (int nt = 0; nt < 8; ++nt) acc[nt] = (f4v){0.f, 0.f, 0.f, 0.f};
#pragma unroll
    for (int ks = 0; ks < 4; ++ks) {
#pragma unroll
      for (int nt = 0; nt < 8; ++nt) {
        s8v bh = ldfrag(RThi, nt * 16, ks * 32, 136);
        s8v bl = ldfrag(RTlo, nt * 16, ks * 32, 136);
        acc[nt] = MFMA(Shi[ks], bh, acc[nt]);
        acc[nt] = MFMA(Slo[ks], bh, acc[nt]);
        acc[nt] = MFMA(Shi[ks], bl, acc[nt]);
      }
    }
    __syncthreads();
    const int row0 = mr + g_ * 4;
#pragma unroll
    for (int nt = 0; nt < 8; ++nt) {
      const int col = nt * 16 + c_;
      s4v hi, lo;
#pragma unroll
      for (int r = 0; r < 4; ++r) {
        float v = acc[nt][r];
        short h = f2b(v);
        hi[r] = h;
        lo[r] = f2b(v - b2f(h));
      }
      *(s4v*)(RThi + col * 136 + row0) = hi;
      *(s4v*)(RTlo + col * 136 + row0) = lo;
    }
    __syncthreads();
  }

  // ---- W2K = K @ phi_W2 (accs in regs; reads RT + raw sW2) ----
  f4v acc[6];
  {
    s8v Shi[4], Slo[4];
#pragma unroll
    for (int ks = 0; ks < 4; ++ks) {
      int m = mr + c_;
      int k0 = ks * 32 + g_ * 8;
#pragma unroll
      for (int i = 0; i < 8; ++i) {
        Shi[ks][i] = RThi[(k0 + i) * 136 + m];
        Slo[ks][i] = RTlo[(k0 + i) * 136 + m];
      }
    }
#pragma unroll
    for (int nt = 0; nt < 6; ++nt) acc[nt] = (f4v){0.f, 0.f, 0.f, 0.f};
#pragma unroll
    for (int ks = 0; ks < 4; ++ks) {
#pragma unroll
      for (int nt = 0; nt < 6; ++nt) {
        s8v bh, bl;
#pragma unroll
        for (int i = 0; i < 8; ++i) {
          float v = sW2[(ks * 32 + g_ * 8 + i) * 96 + nt * 16 + c_];
          short h = f2b(v);
          bh[i] = h;
          bl[i] = f2b(v - b2f(h));
        }
        acc[nt] = MFMA(Shi[ks], bh, acc[nt]);
        acc[nt] = MFMA(Slo[ks], bh, acc[nt]);
        acc[nt] = MFMA(Shi[ks], bl, acc[nt]);
      }
    }
  }
  __syncthreads();   // all raw-sW2 reads complete -> region reusable

  // ---- M1 + W2K: scatter into sW2-region staging, coalesced copy out ----
  short* m1st = (short*)sW2;        // 8192 shorts (16KB)
  short* w2st = m1st + 8192;        // 12288 shorts (24KB)
  for (int e = tid; e < 8192; e += 512) {
    int n = e >> 6, kk = e & 63;
    float v = b2f(RThi[kk * 136 + n]) + b2f(RTlo[kk * 136 + n]);
    m1st[fragidx(n, kk, 2)] = f2b(v);
  }
#pragma unroll
  for (int nt = 0; nt < 6; ++nt)
#pragma unroll
    for (int r = 0; r < 4; ++r)
      w2st[fragidx(mr + g_ * 4 + r, phinv(nt * 16 + c_), 3)] = f2b(acc[nt][r]);
  __syncthreads();
  for (int i = tid; i < 1024; i += 512)
    ((f4v*)(wsp + WS_M1))[i] = ((const f4v*)m1st)[i];
  for (int i = tid; i < 1536; i += 512)
    ((f4v*)(wsp + WS_W2K))[i] = ((const f4v*)w2st)[i];
}

// ---------------------------------------------------------------------------
// Kernel 2: r16 structure (VERIFIED BEST: main ~86us, VGPR 84, 0 spill,
// 0 conflicts). fb-outer stages (weights read once/mt: 104 LDS ops), Z via
// per-wave LDS (register-relief valve — removing it spills, r14), X prefetch
// re-issued after stage 3. Zero in-loop barriers.
// ---------------------------------------------------------------------------
__global__ __launch_bounds__(512, 2) void koop_main(
    const float* __restrict__ xg, const float* __restrict__ b1g,
    const float* __restrict__ bi1g, const float* __restrict__ bi2g,
    const short* __restrict__ wsp, float* __restrict__ outg) {
  extern __shared__ __align__(16) char smem[];
  short* sW = (short*)smem;                  // 45056 shorts = 90112 B
  float* sB = (float*)(smem + 90112);        // b1[96] bi1[96] bi2[64]
  short* zls = (short*)(smem + 92160 + (threadIdx.x >> 6) * 8192);  // 8KB/wave

  const int tid = threadIdx.x, lane = tid & 63, wid = tid >> 6;
  const int c_ = lane & 15, g_ = lane >> 4;

  for (int i = tid; i < 45056 / 8; i += 512)
    ((f4v*)sW)[i] = ((const f4v*)wsp)[i];
  if (tid < 96) sB[tid] = b1g[tid];
  else if (tid < 192) sB[tid] = bi1g[tid - 96];
  else if (tid < 256) sB[tid] = bi2g[tid - 192];
  __syncthreads();   // the only barrier

  const short* wM1  = sW + WS_M1;
  const short* wI1  = sW + WS_I1;
  const short* wW1  = sW + WS_W1;
  const short* wW2K = sW + WS_W2K;
  const short* wI2  = sW + WS_I2;

  const int w = blockIdx.x * 8 + wid;        // 0..2047

  // ---- prologue: load X(tile0) into regs ----
  f4v xv[8];
  {
    const size_t r0 = (size_t)w * 32;
#pragma unroll
    for (int bb = 0; bb < 2; ++bb)
#pragma unroll
      for (int ks = 0; ks < 2; ++ks) {
        const float* p = xg + (r0 + bb * 16 + c_) * 64 + ks * 32 + g_ * 8;
        xv[(bb * 2 + ks) * 2 + 0] = *(const f4v*)p;
        xv[(bb * 2 + ks) * 2 + 1] = *(const f4v*)(p + 4);
      }
  }

  for (int mt = w; mt < NMT; mt += NWAVE) {
    const size_t r0 = (size_t)mt * 32;

    // pack current X (xv dies here)
    s8v bx[2][2];
#pragma unroll
    for (int bb = 0; bb < 2; ++bb)
#pragma unroll
      for (int ks = 0; ks < 2; ++ks)
        bx[bb][ks] = pack8(xv[(bb * 2 + ks) * 2], xv[(bb * 2 + ks) * 2 + 1]);

    // ---- stage 1: H = relu(W1 . X^T + b1): 96 feats -> hbw[bb][3] ----
    u32x4 hbw[2][3];
#pragma unroll
    for (int fb = 0; fb < 6; ++fb) {
      s8v w0 = ldw(wW1, fb * 2 + 0), w1 = ldw(wW1, fb * 2 + 1);
      f4v bias = *(const f4v*)(sB + fb * 16 + g_ * 4);
#pragma unroll
      for (int bb = 0; bb < 2; ++bb) {
        f4v a = bias;
        a = MFMA(w0, bx[bb][0], a);
        a = MFMA(w1, bx[bb][1], a);
        hbw[bb][fb >> 1][(fb & 1) * 2 + 0] = pk2r(a[0], a[1]);
        hbw[bb][fb >> 1][(fb & 1) * 2 + 1] = pk2r(a[2], a[3]);
      }
    }

    // ---- stage 2: Z = M1 . X^T + W2K . H^T -> per-wave LDS (b128/chunk) ----
#pragma unroll
    for (int fbp = 0; fbp < 4; ++fbp) {
      u32x4 zw0, zw1;
#pragma unroll
      for (int sub = 0; sub < 2; ++sub) {
        const int fb = fbp * 2 + sub;
        s8v m0 = ldw(wM1, fb * 2 + 0), m1 = ldw(wM1, fb * 2 + 1);
        s8v k0 = ldw(wW2K, fb * 3 + 0), k1 = ldw(wW2K, fb * 3 + 1), k2 = ldw(wW2K, fb * 3 + 2);
        {
          f4v a = (f4v){0.f, 0.f, 0.f, 0.f};
          a = MFMA(m0, bx[0][0], a);
          a = MFMA(m1, bx[0][1], a);
          a = MFMA(k0, BCV(hbw[0][0]), a);
          a = MFMA(k1, BCV(hbw[0][1]), a);
          a = MFMA(k2, BCV(hbw[0][2]), a);
          zw0[sub * 2 + 0] = pk2(a[0], a[1]);
          zw0[sub * 2 + 1] = pk2(a[2], a[3]);
        }
        {
          f4v a = (f4v){0.f, 0.f, 0.f, 0.f};
          a = MFMA(m0, bx[1][0], a);
          a = MFMA(m1, bx[1][1], a);
          a = MFMA(k0, BCV(hbw[1][0]), a);
          a = MFMA(k1, BCV(hbw[1][1]), a);
          a = MFMA(k2, BCV(hbw[1][2]), a);
          zw1[sub * 2 + 0] = pk2(a[0], a[1]);
          zw1[sub * 2 + 1] = pk2(a[2], a[3]);
        }
      }
      *(u32x4*)(zls + (0 + fbp) * 512 + lane * 8) = zw0;   // bb=0: chunks 0..3
      *(u32x4*)(zls + (4 + fbp) * 512 + lane * 8) = zw1;   // bb=1: chunks 4..7
    }

    // ---- read Z back (8 conflict-free b128) ----
    s8v zb[2][4];
#pragma unroll
    for (int bb = 0; bb < 2; ++bb)
#pragma unroll
      for (int ks = 0; ks < 4; ++ks)
        zb[bb][ks] = *(const s8v*)(zls + (bb * 4 + ks) * 512 + lane * 8);

    // ---- stage 3: H2 = relu(I1 . Z^T + bi1): fb-outer, weights once ----
    u32x4 h2w[2][3];
#pragma unroll
    for (int fb = 0; fb < 6; ++fb) {
      s8v i0 = ldw(wI1, fb * 4 + 0), i1 = ldw(wI1, fb * 4 + 1);
      s8v i2 = ldw(wI1, fb * 4 + 2), i3 = ldw(wI1, fb * 4 + 3);
      f4v bias = *(const f4v*)(sB + 96 + fb * 16 + g_ * 4);
#pragma unroll
      for (int bb = 0; bb < 2; ++bb) {
        f4v a = bias;
        a = MFMA(i0, zb[bb][0], a);
        a = MFMA(i1, zb[bb][1], a);
        a = MFMA(i2, zb[bb][2], a);
        a = MFMA(i3, zb[bb][3], a);
        h2w[bb][fb >> 1][(fb & 1) * 2 + 0] = pk2r(a[0], a[1]);
        h2w[bb][fb >> 1][(fb & 1) * 2 + 1] = pk2r(a[2], a[3]);
      }
    }

    // issue next-tile X loads (after the stage-2/3 register peaks; latency
    // hides under stage 4 + next loop-top with the co-resident wave)
    if (mt + NWAVE < NMT) {
      const size_t r1 = (size_t)(mt + NWAVE) * 32;
#pragma unroll
      for (int bb = 0; bb < 2; ++bb)
#pragma unroll
        for (int ks = 0; ks < 2; ++ks) {
          const float* p = xg + (r1 + bb * 16 + c_) * 64 + ks * 32 + g_ * 8;
          xv[(bb * 2 + ks) * 2 + 0] = *(const f4v*)p;
          xv[(bb * 2 + ks) * 2 + 1] = *(const f4v*)(p + 4);
        }
    }

    // ---- stage 4: OUT = I2 . H2^T + bi2: fb-outer, weights once ----
#pragma unroll
    for (int fb = 0; fb < 4; ++fb) {
      s8v j0 = ldw(wI2, fb * 3 + 0), j1 = ldw(wI2, fb * 3 + 1), j2 = ldw(wI2, fb * 3 + 2);
      f4v bias = *(const f4v*)(sB + 192 + fb * 16 + g_ * 4);
#pragma unroll
      for (int bb = 0; bb < 2; ++bb) {
        f4v a = bias;
        a = MFMA(j0, BCV(h2w[bb][0]), a);
        a = MFMA(j1, BCV(h2w[bb][1]), a);
        a = MFMA(j2, BCV(h2w[bb][2]), a);
        *(f4v*)(outg + (r0 + bb * 16 + c_) * 64 + fb * 16 + g_ * 4) = a;
      }
    }
  }
}

#define PREP_LDS (128 * 136 * 2 * 2 + 128 * 96 * 4 + 130 * 4)   // 119304 B
#define MAIN_LDS (92160 + 8 * 8192)                              // 157696 B

extern "C" void kernel_launch(void* const* d_in, const int* in_sizes, int n_in,
                              void* d_out, int out_size, void* d_ws, size_t ws_size,
                              hipStream_t stream) {
  (void)in_sizes; (void)n_in; (void)out_size; (void)ws_size;
  const float* t     = (const float*)d_in[0];
  const float* x     = (const float*)d_in[1];
  const float* A     = (const float*)d_in[2];
  const float* phiW1 = (const float*)d_in[3];
  const float* phib1 = (const float*)d_in[4];
  const float* phiW2 = (const float*)d_in[5];
  const float* invW1 = (const float*)d_in[6];
  const float* invb1 = (const float*)d_in[7];
  const float* invW2 = (const float*)d_in[8];
  const float* invb2 = (const float*)d_in[9];
  float* out = (float*)d_out;
  short* wsp = (short*)d_ws;

  (void)hipFuncSetAttribute((const void*)koop_prep,
                            hipFuncAttributeMaxDynamicSharedMemorySize, PREP_LDS);
  (void)hipFuncSetAttribute((const void*)koop_main,
                            hipFuncAttributeMaxDynamicSharedMemorySize, MAIN_LDS);

  koop_prep<<<1, 512, PREP_LDS, stream>>>(t, A, phiW2, phiW1, invW1, invW2, wsp);
  koop_main<<<256, 512, MAIN_LDS, stream>>>(x, phib1, invb1, invb2, wsp, out);
}